// Round 12
// baseline (3066.692 us; speedup 1.0000x reference)
//
#include <hip/hip_runtime.h>

#define BB 256
#define TT 512
#define HH 512
#define G4 2048
#define NTHR 512
#define NWG 256
#define GROUPS 8
#define SLICES 32
#define HTOT (BB*HH)

// bar word layout
#define DCNT     8192
#define DGEN     8208
#define XCCOF(g) (8224+(g))
#define BADF(g)  (8240+(g))
#define GCNT(g)  (8704+(g)*32)      // per-group step counter, own 128-B line

typedef __attribute__((ext_vector_type(8))) short short8;
typedef __attribute__((ext_vector_type(4))) float f32x4;

__device__ __forceinline__ ushort bf16r(float f) {          // RNE fp32->bf16
    unsigned u = __float_as_uint(f);
    return (ushort)((u + 0x7FFFu + ((u >> 16) & 1u)) >> 16);
}
__device__ __forceinline__ float bf16f(ushort s) {
    return __uint_as_float(((unsigned)s) << 16);
}
__device__ __forceinline__ float fsig(float x) {
    float e = exp2f(fminf(-1.44269504f * x, 80.f));
    return 1.f / (1.f + e);
}
__device__ __forceinline__ float ftanh(float x) {
    float e = exp2f(fminf(-2.88539008f * x, 80.f));
    return (1.f - e) / (1.f + e);
}

#define WAITV(n) do { asm volatile("s_waitcnt vmcnt(" #n ")" ::: "memory"); \
                      __builtin_amdgcn_sched_barrier(0); } while (0)

// one-shot data accesses (h planes). Sync ALWAYS uses atomic instructions (r10 law);
// FAST executes them at the XCD-local TCC (no sc1), SAFE at MALL (agent scope).
template<bool SC1>
__device__ __forceinline__ void lda16(short8* d, const ushort* p) {
    if constexpr (SC1)
        asm volatile("global_load_dwordx4 %0, %1, off sc0 sc1" : "=v"(*d) : "v"(p));
    else
        asm volatile("global_load_dwordx4 %0, %1, off sc0" : "=v"(*d) : "v"(p));
}
template<bool SC1>
__device__ __forceinline__ void sts2(ushort* p, unsigned v) {
    if constexpr (SC1)
        asm volatile("global_store_short %0, %1, off sc0 sc1" :: "v"(p), "v"(v) : "memory");
    else
        asm volatile("global_store_short %0, %1, off" :: "v"(p), "v"(v) : "memory");
}
template<bool FAST>
__device__ __forceinline__ void cnt_add1(unsigned* p) {
    if constexpr (FAST) {
        unsigned one = 1u;
        asm volatile("global_atomic_add %0, %1, off" :: "v"(p), "v"(one) : "memory");
    } else {
        __hip_atomic_fetch_add(p, 1u, __ATOMIC_RELAXED, __HIP_MEMORY_SCOPE_AGENT);
    }
}
template<bool FAST>
__device__ __forceinline__ unsigned cnt_read(unsigned* p) {
    if constexpr (FAST) {
        unsigned old, z = 0u;
        asm volatile("global_atomic_add %0, %1, %2, off sc0\n\ts_waitcnt vmcnt(0)"
                     : "=v"(old) : "v"(p), "v"(z) : "memory");
        return old;
    } else {
        return __hip_atomic_load(p, __ATOMIC_RELAXED, __HIP_MEMORY_SCOPE_AGENT);
    }
}

__device__ void dev_barrier(unsigned* bar) {
    __syncthreads();
    if (threadIdx.x == 0) {
        unsigned old = __hip_atomic_load(bar + DGEN, __ATOMIC_RELAXED, __HIP_MEMORY_SCOPE_AGENT);
        unsigned a = __hip_atomic_fetch_add(bar + DCNT, 1u, __ATOMIC_RELAXED, __HIP_MEMORY_SCOPE_AGENT);
        if (a == NWG - 1) {
            __hip_atomic_store(bar + DCNT, 0u, __ATOMIC_RELAXED, __HIP_MEMORY_SCOPE_AGENT);
            __hip_atomic_fetch_add(bar + DGEN, 1u, __ATOMIC_RELAXED, __HIP_MEMORY_SCOPE_AGENT);
        } else {
            int sp = 0;
            while (__hip_atomic_load(bar + DGEN, __ATOMIC_RELAXED, __HIP_MEMORY_SCOPE_AGENT) == old
                   && ++sp < (1 << 20))
                __builtin_amdgcn_s_sleep(2);
        }
    }
    __syncthreads();
}

template<bool FAST>
__device__ void run_steps(const float* __restrict__ x, const float* __restrict__ lns,
                          const float* __restrict__ lnb, const float* __restrict__ Wd,
                          const float* __restrict__ bd, float* __restrict__ out,
                          ushort* __restrict__ hbHi, ushort* __restrict__ hbMid,
                          unsigned* __restrict__ bar, short* sWhi, short* sWmid,
                          float* zL, float* sWi, float* sBias, float* sX,
                          int g, int slice)
{
    const int tid = threadIdx.x;
    const int wave = tid >> 6, lane = tid & 63;
    const int ks = wave & 1, gp = (wave >> 1) & 1, rt = (wave >> 2) & 1;
    const int cl = lane & 15, kq4 = (lane >> 4) << 2, kq8 = (lane >> 4) << 3;
    const int grow0 = g * 32, hid0 = slice * 16;
    const int rbase = rt * 16 + kq4;
    const int arow = grow0 + rt * 16 + cl;
    const int bswz = (cl & 7) << 3;
    const int cA = gp * 32 + cl, cB = cA + 16;
    // gate-phase mapping: one (row, hidden-unit) per thread
    const int grow = tid >> 4, ghq = tid & 15, glc = ghq << 2;

    float creg = 0.f;

    for (int it = 0; it <= TT; ++it) {
        const ushort* hiIn = hbHi + (size_t)(it & 1) * HTOT;
        const ushort* mdIn = hbMid + (size_t)(it & 1) * HTOT;
        ushort* hiOut = hbHi + (size_t)((it + 1) & 1) * HTOT;
        ushort* mdOut = hbMid + (size_t)((it + 1) & 1) * HTOT;

        if (it < TT) {
            // ---- stage this step's x tile (32 rows x 3) into LDS ----
            if (tid < 32) {
                const float* xp = x + ((size_t)(grow0 + tid) * TT + it) * 3;
                sX[tid * 3 + 0] = xp[0];
                sX[tid * 3 + 1] = xp[1];
                sX[tid * 3 + 2] = xp[2];
            }
            // ---- h @ Wh partials: 3-pass split-bf16 MFMA (K-split by ks) ----
            f32x4 acc0 = {0.f,0.f,0.f,0.f}, acc1 = {0.f,0.f,0.f,0.f};
            if (it > 0) {
                const ushort* aHi = hiIn + (size_t)arow * HH + ks*256 + kq8;
                const ushort* aMd = mdIn + (size_t)arow * HH + ks*256 + kq8;
                short8 A[16];
                WAITV(0);                       // clean FIFO -> exact counts
                #pragma unroll
                for (int kc = 0; kc < 8; ++kc) {
                    lda16<!FAST>(&A[kc*2],   aHi + kc*32);
                    lda16<!FAST>(&A[kc*2+1], aMd + kc*32);
                }
                #pragma unroll
                for (int kc = 0; kc < 8; ++kc) {
                    if      (kc == 0) WAITV(14);
                    else if (kc == 1) WAITV(12);
                    else if (kc == 2) WAITV(10);
                    else if (kc == 3) WAITV(8);
                    else if (kc == 4) WAITV(6);
                    else if (kc == 5) WAITV(4);
                    else if (kc == 6) WAITV(2);
                    else              WAITV(0);
                    int k0 = ks*256 + kc*32 + kq8;
                    int boA = cA*512 + (k0 ^ bswz);
                    int boB = cB*512 + (k0 ^ bswz);
                    short8 Ah = A[kc*2], Am = A[kc*2+1];
                    short8 BhA = *(const short8*)&sWhi[boA];
                    short8 BmA = *(const short8*)&sWmid[boA];
                    short8 BhB = *(const short8*)&sWhi[boB];
                    short8 BmB = *(const short8*)&sWmid[boB];
                    acc0 = __builtin_amdgcn_mfma_f32_16x16x32_bf16(Ah, BhA, acc0, 0,0,0);
                    acc1 = __builtin_amdgcn_mfma_f32_16x16x32_bf16(Ah, BhB, acc1, 0,0,0);
                    acc0 = __builtin_amdgcn_mfma_f32_16x16x32_bf16(Ah, BmA, acc0, 0,0,0);
                    acc1 = __builtin_amdgcn_mfma_f32_16x16x32_bf16(Ah, BmB, acc1, 0,0,0);
                    acc0 = __builtin_amdgcn_mfma_f32_16x16x32_bf16(Am, BhA, acc0, 0,0,0);
                    acc1 = __builtin_amdgcn_mfma_f32_16x16x32_bf16(Am, BhB, acc1, 0,0,0);
                }
            }
            // ---- publish partials to LDS: zL[ks][row][col], col-stride 68 ----
            #pragma unroll
            for (int q = 0; q < 4; ++q) {
                zL[(ks*32 + rbase + q)*68 + cA] = acc0[q];
                zL[(ks*32 + rbase + q)*68 + cB] = acc1[q];
            }
            __syncthreads();

            // ---- gate phase: 1 (row, hidden) unit per thread, no shuffles ----
            {
                f32x4 z0 = *(const f32x4*)&zL[grow*68 + glc];
                f32x4 z1 = *(const f32x4*)&zL[2176 + grow*68 + glc];
                float x0 = sX[grow*3+0], x1 = sX[grow*3+1], x2 = sX[grow*3+2];
                float z[4];
                #pragma unroll
                for (int g3 = 0; g3 < 4; ++g3)
                    z[g3] = z0[g3] + z1[g3] + sBias[glc+g3] + x0*sWi[glc+g3]
                          + x1*sWi[64+glc+g3] + x2*sWi[128+glc+g3];
                float ig = fsig(z[0]), fg = fsig(z[1]);
                float gv = ftanh(z[2]), og = fsig(z[3]);
                creg = fg * creg + ig * gv;
                float hv = og * ftanh(creg);
                ushort h0 = bf16r(hv);
                ushort h1 = bf16r(hv - bf16f(h0));
                size_t ridx = (size_t)(grow0 + grow) * HH + hid0 + ghq;
                sts2<!FAST>(hiOut + ridx, (unsigned)h0);
                sts2<!FAST>(mdOut + ridx, (unsigned)h1);
            }
            __syncthreads();                  // drains h stores into L2 (vmcnt0)
            if (tid == 0)                     // single-hop barrier arrive (atomic)
                cnt_add1<FAST>(&bar[GCNT(g)]);
        }

        // ---- output head for t=it-1 on wave 1 only (wave-local, no syncs) ----
        if (it >= 1 && wave == 1) {
            const int row_h = grow0 + slice;
            const ushort* hp = hiIn + (size_t)row_h * HH + lane * 8;
            short8 vh, vm;
            lda16<!FAST>(&vh, hp);
            lda16<!FAST>(&vm, mdIn + (size_t)row_h * HH + lane * 8);
            WAITV(0);
            float h[8]; float s = 0.f, ss = 0.f;
            #pragma unroll
            for (int j = 0; j < 8; ++j) {
                h[j] = bf16f((ushort)vh[j]) + bf16f((ushort)vm[j]);
                s += h[j]; ss += h[j] * h[j];
            }
            #pragma unroll
            for (int d = 1; d < 64; d <<= 1) { s += __shfl_xor(s, d); ss += __shfl_xor(ss, d); }
            float mu = s * (1.f / 512.f);
            float rstd = rsqrtf(ss * (1.f / 512.f) - mu * mu + 1e-6f);
            float d0 = 0.f, d1 = 0.f, d2 = 0.f;
            #pragma unroll
            for (int j = 0; j < 8; ++j) {
                int col = lane * 8 + j;
                float y = (h[j] - mu) * rstd * lns[col] + lnb[col];
                y = fmaxf(y, 0.f);
                d0 = fmaf(y, Wd[col*3+0], d0);
                d1 = fmaf(y, Wd[col*3+1], d1);
                d2 = fmaf(y, Wd[col*3+2], d2);
            }
            #pragma unroll
            for (int d = 1; d < 64; d <<= 1) {
                d0 += __shfl_xor(d0, d); d1 += __shfl_xor(d1, d); d2 += __shfl_xor(d2, d);
            }
            if (lane == 0) {
                size_t o = ((size_t)row_h * TT + (it - 1)) * 3;
                out[o + 0] = d0 + bd[0];
                out[o + 1] = d1 + bd[1];
                out[o + 2] = d2 + bd[2];
            }
        }

        if (it < TT) {   // ---- single-hop barrier wait: poll group counter ----
            if (wave == 0 && lane == 0) {
                const unsigned tgt = (unsigned)(SLICES * (it + 1));
                int spins = 0;
                while (cnt_read<FAST>(&bar[GCNT(g)]) < tgt) {
                    if (++spins > (1 << 16)) break;
                    if constexpr (!FAST) __builtin_amdgcn_s_sleep(1);
                }
            }
            __syncthreads();
        }
    }
}

__global__ __launch_bounds__(NTHR, 1)
void lstm_v12(const float* __restrict__ x, const float* __restrict__ Wi,
              const float* __restrict__ Wh, const float* __restrict__ bias,
              const float* __restrict__ lns, const float* __restrict__ lnb,
              const float* __restrict__ Wd, const float* __restrict__ bd,
              float* __restrict__ out, ushort* __restrict__ hbHi,
              ushort* __restrict__ hbMid, unsigned* __restrict__ bar)
{
    extern __shared__ char smem[];
    short* sWhi  = (short*)smem;                    // [64][512] swizzled  64 KB
    short* sWmid = (short*)(smem + 65536);          // [64][512] swizzled  64 KB
    float* zL    = (float*)(smem + 131072);         // [2][32][68] f32   17408 B
    float* sWi   = (float*)(smem + 148480);         // [3][64]
    float* sBias = (float*)(smem + 149248);         // [64]
    float* sX    = (float*)(smem + 149504);         // [32][3] (+pad)
    unsigned* sFlag = (unsigned*)(smem + 150016);

    const int bid = blockIdx.x, tid = threadIdx.x;
    const int g = bid & 7, slice = bid >> 3;        // group = XCD under round-robin
    const int hid0 = slice * 16;

    // ---- prologue: decompose W slice (64 gc x 512 k) into 2 LDS planes ----
    for (int cc = tid; cc < 4096; cc += NTHR) {
        int col = cc & 63, k0 = (cc >> 6) << 3;
        int gc = ((col & 3) << 9) + hid0 + (col >> 2);   // gate*512 + hid
        short8 vh, vm;
        #pragma unroll
        for (int j = 0; j < 8; ++j) {
            float w = Wh[(size_t)(k0 + j) * G4 + gc];
            ushort c0 = bf16r(w);
            vh[j] = (short)c0; vm[j] = (short)bf16r(w - bf16f(c0));
        }
        int base = col * 512 + (k0 ^ ((col & 7) << 3));
        *(short8*)&sWhi[base]  = vh;
        *(short8*)&sWmid[base] = vm;
    }
    if (tid < 64) {
        int gc = ((tid & 3) << 9) + hid0 + (tid >> 2);
        sBias[tid] = bias[gc];
        #pragma unroll
        for (int f = 0; f < 3; ++f) sWi[f * 64 + tid] = Wi[(size_t)f * G4 + gc];
    }

    // ---- placement detection: is group g XCD-uniform? ----
    unsigned xcc;
    asm volatile("s_getreg_b32 %0, hwreg(HW_REG_XCC_ID)" : "=s"(xcc));
    if (tid == 0 && slice == 0)
        __hip_atomic_store(&bar[XCCOF(g)], xcc, __ATOMIC_RELAXED, __HIP_MEMORY_SCOPE_AGENT);
    dev_barrier(bar);
    if (tid == 0) {
        unsigned lx = __hip_atomic_load(&bar[XCCOF(g)], __ATOMIC_RELAXED,
                                        __HIP_MEMORY_SCOPE_AGENT);
        if (lx != xcc)
            __hip_atomic_fetch_or(&bar[BADF(g)], 1u, __ATOMIC_RELAXED,
                                  __HIP_MEMORY_SCOPE_AGENT);
    }
    dev_barrier(bar);
    if (tid == 0)
        sFlag[0] = (__hip_atomic_load(&bar[BADF(g)], __ATOMIC_RELAXED,
                                      __HIP_MEMORY_SCOPE_AGENT) == 0u) ? 1u : 0u;
    __syncthreads();

    if (sFlag[0])
        run_steps<true >(x, lns, lnb, Wd, bd, out, hbHi, hbMid, bar,
                         sWhi, sWmid, zL, sWi, sBias, sX, g, slice);
    else
        run_steps<false>(x, lns, lnb, Wd, bd, out, hbHi, hbMid, bar,
                         sWhi, sWmid, zL, sWi, sBias, sX, g, slice);
}

extern "C" void kernel_launch(void* const* d_in, const int* in_sizes, int n_in,
                              void* d_out, int out_size, void* d_ws, size_t ws_size,
                              hipStream_t stream) {
    const float* x   = (const float*)d_in[0];
    const float* Wi  = (const float*)d_in[1];
    const float* Wh  = (const float*)d_in[2];
    const float* b   = (const float*)d_in[3];
    const float* lns = (const float*)d_in[4];
    const float* lnb = (const float*)d_in[5];
    const float* Wd  = (const float*)d_in[6];
    const float* bd  = (const float*)d_in[7];
    float* out = (float*)d_out;

    // ws: hbHi 2x256x512 ushort (512 KB) | hbMid (512 KB) | bar (~40 KB)
    ushort* hbHi  = (ushort*)d_ws;
    ushort* hbMid = hbHi + (size_t)2 * HTOT;
    unsigned* bar = (unsigned*)(hbMid + (size_t)2 * HTOT);

    hipMemsetAsync(bar, 0, 40960, stream);

    size_t smem = 150032;
    hipFuncSetAttribute((const void*)lstm_v12,
                        hipFuncAttributeMaxDynamicSharedMemorySize, (int)smem);

    void* args[] = { (void*)&x, (void*)&Wi, (void*)&Wh, (void*)&b, (void*)&lns,
                     (void*)&lnb, (void*)&Wd, (void*)&bd, (void*)&out,
                     (void*)&hbHi, (void*)&hbMid, (void*)&bar };
    hipLaunchCooperativeKernel((void*)lstm_v12, dim3(NWG), dim3(NTHR),
                               args, (unsigned int)smem, stream);
}

// Round 13
// 2862.272 us; speedup vs baseline: 1.0714x; 1.0714x over previous
//
#include <hip/hip_runtime.h>

#define BB 256
#define TT 512
#define HH 512
#define G4 2048
#define NTHR 512
#define NWG 256
#define GROUPS 8
#define SLICES 32
#define HTOT (BB*HH)

// bar word layout: per-(g,slice) flag on its own 128-B line, then control words
#define FLAGW(g,s) ((((g)*SLICES)+(s))*32)
#define DCNT     8192
#define DGEN     8208
#define XCCOF(g) (8224+(g))
#define BADF(g)  (8240+(g))

typedef __attribute__((ext_vector_type(8))) short short8;
typedef __attribute__((ext_vector_type(4))) float f32x4;

__device__ __forceinline__ ushort bf16r(float f) {          // RNE fp32->bf16
    unsigned u = __float_as_uint(f);
    return (ushort)((u + 0x7FFFu + ((u >> 16) & 1u)) >> 16);
}
__device__ __forceinline__ float bf16f(ushort s) {
    return __uint_as_float(((unsigned)s) << 16);
}
__device__ __forceinline__ float fsig(float x) {
    float e = exp2f(fminf(-1.44269504f * x, 80.f));
    return 1.f / (1.f + e);
}
__device__ __forceinline__ float ftanh(float x) {
    float e = exp2f(fminf(-2.88539008f * x, 80.f));
    return (1.f - e) / (1.f + e);
}

#define WAITV(n) do { asm volatile("s_waitcnt vmcnt(" #n ")" ::: "memory"); \
                      __builtin_amdgcn_sched_barrier(0); } while (0)

// one-shot data accesses (h planes). Flag polling is ALWAYS atomic (r9/r10 law).
template<bool SC1>
__device__ __forceinline__ void lda16(short8* d, const ushort* p) {
    if constexpr (SC1)
        asm volatile("global_load_dwordx4 %0, %1, off sc0 sc1" : "=v"(*d) : "v"(p));
    else
        asm volatile("global_load_dwordx4 %0, %1, off sc0" : "=v"(*d) : "v"(p));
}
template<bool SC1>
__device__ __forceinline__ void sts2(ushort* p, unsigned v) {
    if constexpr (SC1)
        asm volatile("global_store_short %0, %1, off sc0 sc1" :: "v"(p), "v"(v) : "memory");
    else
        asm volatile("global_store_short %0, %1, off" :: "v"(p), "v"(v) : "memory");
}

__device__ void dev_barrier(unsigned* bar) {
    __syncthreads();
    if (threadIdx.x == 0) {
        unsigned old = __hip_atomic_load(bar + DGEN, __ATOMIC_RELAXED, __HIP_MEMORY_SCOPE_AGENT);
        unsigned a = __hip_atomic_fetch_add(bar + DCNT, 1u, __ATOMIC_RELAXED, __HIP_MEMORY_SCOPE_AGENT);
        if (a == NWG - 1) {
            __hip_atomic_store(bar + DCNT, 0u, __ATOMIC_RELAXED, __HIP_MEMORY_SCOPE_AGENT);
            __hip_atomic_fetch_add(bar + DGEN, 1u, __ATOMIC_RELAXED, __HIP_MEMORY_SCOPE_AGENT);
        } else {
            int sp = 0;
            while (__hip_atomic_load(bar + DGEN, __ATOMIC_RELAXED, __HIP_MEMORY_SCOPE_AGENT) == old
                   && ++sp < (1 << 20))
                __builtin_amdgcn_s_sleep(2);
        }
    }
    __syncthreads();
}

template<bool FAST>
__device__ void run_steps(const float* __restrict__ x, const float* __restrict__ lns,
                          const float* __restrict__ lnb, const float* __restrict__ Wd,
                          const float* __restrict__ bd, float* __restrict__ out,
                          ushort* __restrict__ hbHi, ushort* __restrict__ hbMid,
                          unsigned* __restrict__ bar, short* sWhi, short* sWmid,
                          float* zL, float* sWi, float* sBias, float* sX,
                          int g, int slice)
{
    const int tid = threadIdx.x;
    const int wave = tid >> 6, lane = tid & 63;
    const int ks = wave & 1, gp = (wave >> 1) & 1, rt = (wave >> 2) & 1;
    const int cl = lane & 15, kq4 = (lane >> 4) << 2, kq8 = (lane >> 4) << 3;
    const int grow0 = g * 32, hid0 = slice * 16;
    const int rbase = rt * 16 + kq4;
    const int arow = grow0 + rt * 16 + cl;
    const int bswz = (cl & 7) << 3;
    const int cA = gp * 32 + cl, cB = cA + 16;
    // gate-phase mapping: one (row, hidden-unit) per thread
    const int grow = tid >> 4, ghq = tid & 15, glc = ghq << 2;

    float creg = 0.f;

    // prologue: stage x for it = 0
    if (tid < 32) {
        const float* xp = x + ((size_t)(grow0 + tid) * TT + 0) * 3;
        sX[tid*3+0] = xp[0]; sX[tid*3+1] = xp[1]; sX[tid*3+2] = xp[2];
    }
    __syncthreads();

    for (int it = 0; it <= TT; ++it) {
        const ushort* hiIn = hbHi + (size_t)(it % 3) * HTOT;
        const ushort* mdIn = hbMid + (size_t)(it % 3) * HTOT;
        ushort* hiOut = hbHi + (size_t)((it + 1) % 3) * HTOT;
        ushort* mdOut = hbMid + (size_t)((it + 1) % 3) * HTOT;
        const float* sXc = sX + (it & 1) * 96;
        float*       sXn = sX + ((it + 1) & 1) * 96;

        if (it < TT) {
            // ---- h @ Wh partials: dataflow-gated 3-pass split-bf16 MFMA ----
            f32x4 acc0 = {0.f,0.f,0.f,0.f}, acc1 = {0.f,0.f,0.f,0.f};
            if (it > 0) {
                // per-wave producer gate: this ks-half's 16 producer flags >= it
                {
                    const unsigned tgt = (unsigned)it;
                    int spins = 0;
                    while (true) {
                        unsigned v = tgt;
                        if (lane < 16)
                            v = __hip_atomic_load(&bar[FLAGW(g, ks*16 + lane)],
                                                  __ATOMIC_RELAXED, __HIP_MEMORY_SCOPE_AGENT);
                        if (__all(v >= tgt)) break;
                        if (++spins > (1 << 16)) break;
                    }
                }
                const ushort* aHi = hiIn + (size_t)arow * HH + ks*256 + kq8;
                const ushort* aMd = mdIn + (size_t)arow * HH + ks*256 + kq8;
                short8 A[16];
                #pragma unroll
                for (int kc = 0; kc < 8; ++kc) {
                    lda16<!FAST>(&A[kc*2],   aHi + kc*32);
                    lda16<!FAST>(&A[kc*2+1], aMd + kc*32);
                }
                #pragma unroll
                for (int kc = 0; kc < 8; ++kc) {
                    if      (kc == 0) WAITV(14);
                    else if (kc == 1) WAITV(12);
                    else if (kc == 2) WAITV(10);
                    else if (kc == 3) WAITV(8);
                    else if (kc == 4) WAITV(6);
                    else if (kc == 5) WAITV(4);
                    else if (kc == 6) WAITV(2);
                    else              WAITV(0);
                    int k0 = ks*256 + kc*32 + kq8;
                    int boA = cA*512 + (k0 ^ bswz);
                    int boB = cB*512 + (k0 ^ bswz);
                    short8 Ah = A[kc*2], Am = A[kc*2+1];
                    short8 BhA = *(const short8*)&sWhi[boA];
                    short8 BmA = *(const short8*)&sWmid[boA];
                    short8 BhB = *(const short8*)&sWhi[boB];
                    short8 BmB = *(const short8*)&sWmid[boB];
                    acc0 = __builtin_amdgcn_mfma_f32_16x16x32_bf16(Ah, BhA, acc0, 0,0,0);
                    acc1 = __builtin_amdgcn_mfma_f32_16x16x32_bf16(Ah, BhB, acc1, 0,0,0);
                    acc0 = __builtin_amdgcn_mfma_f32_16x16x32_bf16(Ah, BmA, acc0, 0,0,0);
                    acc1 = __builtin_amdgcn_mfma_f32_16x16x32_bf16(Ah, BmB, acc1, 0,0,0);
                    acc0 = __builtin_amdgcn_mfma_f32_16x16x32_bf16(Am, BhA, acc0, 0,0,0);
                    acc1 = __builtin_amdgcn_mfma_f32_16x16x32_bf16(Am, BhB, acc1, 0,0,0);
                }
            }
            // ---- publish partials to LDS: zL[ks][row][col], col-stride 68 ----
            #pragma unroll
            for (int q = 0; q < 4; ++q) {
                zL[(ks*32 + rbase + q)*68 + cA] = acc0[q];
                zL[(ks*32 + rbase + q)*68 + cB] = acc1[q];
            }
            __syncthreads();

            // ---- gate phase: 1 (row, hidden) unit per thread, no shuffles ----
            {
                f32x4 z0 = *(const f32x4*)&zL[grow*68 + glc];
                f32x4 z1 = *(const f32x4*)&zL[2176 + grow*68 + glc];
                float x0 = sXc[grow*3+0], x1 = sXc[grow*3+1], x2 = sXc[grow*3+2];
                float z[4];
                #pragma unroll
                for (int g3 = 0; g3 < 4; ++g3)
                    z[g3] = z0[g3] + z1[g3] + sBias[glc+g3] + x0*sWi[glc+g3]
                          + x1*sWi[64+glc+g3] + x2*sWi[128+glc+g3];
                float ig = fsig(z[0]), fg = fsig(z[1]);
                float gv = ftanh(z[2]), og = fsig(z[3]);
                creg = fg * creg + ig * gv;
                float hv = og * ftanh(creg);
                ushort h0 = bf16r(hv);
                ushort h1 = bf16r(hv - bf16f(h0));
                size_t ridx = (size_t)(grow0 + grow) * HH + hid0 + ghq;
                sts2<!FAST>(hiOut + ridx, (unsigned)h0);
                sts2<!FAST>(mdOut + ridx, (unsigned)h1);
            }
            // ---- prefetch next step's x into the other sX slot ----
            if (tid < 32 && it + 1 < TT) {
                const float* xp = x + ((size_t)(grow0 + tid) * TT + (it + 1)) * 3;
                sXn[tid*3+0] = xp[0]; sXn[tid*3+1] = xp[1]; sXn[tid*3+2] = xp[2];
            }
            __syncthreads();                  // drains h stores (+x loads) into L2
            if (tid == 0)                     // publish: this wg's h_it is visible
                __hip_atomic_store(&bar[FLAGW(g, slice)], (unsigned)(it + 1),
                                   __ATOMIC_RELAXED, __HIP_MEMORY_SCOPE_AGENT);
        }

        // ---- output head for t=it-1 on wave 1 (availability via step-it gating) ----
        if (it >= 1 && wave == 1) {
            if (it == TT) {   // final: no MFMA gating ran -> explicit 32-flag check
                const unsigned tgt = (unsigned)TT;
                int spins = 0;
                while (true) {
                    unsigned v = tgt;
                    if (lane < 32)
                        v = __hip_atomic_load(&bar[FLAGW(g, lane)],
                                              __ATOMIC_RELAXED, __HIP_MEMORY_SCOPE_AGENT);
                    if (__all(v >= tgt)) break;
                    if (++spins > (1 << 16)) break;
                }
            }
            const int row_h = grow0 + slice;
            const ushort* hp = hiIn + (size_t)row_h * HH + lane * 8;
            short8 vh, vm;
            lda16<!FAST>(&vh, hp);
            lda16<!FAST>(&vm, mdIn + (size_t)row_h * HH + lane * 8);
            WAITV(0);
            float h[8]; float s = 0.f, ss = 0.f;
            #pragma unroll
            for (int j = 0; j < 8; ++j) {
                h[j] = bf16f((ushort)vh[j]) + bf16f((ushort)vm[j]);
                s += h[j]; ss += h[j] * h[j];
            }
            #pragma unroll
            for (int d = 1; d < 64; d <<= 1) { s += __shfl_xor(s, d); ss += __shfl_xor(ss, d); }
            float mu = s * (1.f / 512.f);
            float rstd = rsqrtf(ss * (1.f / 512.f) - mu * mu + 1e-6f);
            float d0 = 0.f, d1 = 0.f, d2 = 0.f;
            #pragma unroll
            for (int j = 0; j < 8; ++j) {
                int col = lane * 8 + j;
                float y = (h[j] - mu) * rstd * lns[col] + lnb[col];
                y = fmaxf(y, 0.f);
                d0 = fmaf(y, Wd[col*3+0], d0);
                d1 = fmaf(y, Wd[col*3+1], d1);
                d2 = fmaf(y, Wd[col*3+2], d2);
            }
            #pragma unroll
            for (int d = 1; d < 64; d <<= 1) {
                d0 += __shfl_xor(d0, d); d1 += __shfl_xor(d1, d); d2 += __shfl_xor(d2, d);
            }
            if (lane == 0) {
                size_t o = ((size_t)row_h * TT + (it - 1)) * 3;
                out[o + 0] = d0 + bd[0];
                out[o + 1] = d1 + bd[1];
                out[o + 2] = d2 + bd[2];
            }
        }
        // NO end-of-step barrier: next step's per-wave flag gates enforce order.
    }
}

__global__ __launch_bounds__(NTHR, 1)
void lstm_v13(const float* __restrict__ x, const float* __restrict__ Wi,
              const float* __restrict__ Wh, const float* __restrict__ bias,
              const float* __restrict__ lns, const float* __restrict__ lnb,
              const float* __restrict__ Wd, const float* __restrict__ bd,
              float* __restrict__ out, ushort* __restrict__ hbHi,
              ushort* __restrict__ hbMid, unsigned* __restrict__ bar)
{
    extern __shared__ char smem[];
    short* sWhi  = (short*)smem;                    // [64][512] swizzled  64 KB
    short* sWmid = (short*)(smem + 65536);          // [64][512] swizzled  64 KB
    float* zL    = (float*)(smem + 131072);         // [2][32][68] f32   17408 B
    float* sWi   = (float*)(smem + 148480);         // [3][64]
    float* sBias = (float*)(smem + 149248);         // [64]
    float* sX    = (float*)(smem + 149504);         // [2][96] x double-buffer
    unsigned* sFlag = (unsigned*)(smem + 150528);

    const int bid = blockIdx.x, tid = threadIdx.x;
    const int g = bid & 7, slice = bid >> 3;        // group = XCD under round-robin
    const int hid0 = slice * 16;

    // ---- prologue: decompose W slice (64 gc x 512 k) into 2 LDS planes ----
    for (int cc = tid; cc < 4096; cc += NTHR) {
        int col = cc & 63, k0 = (cc >> 6) << 3;
        int gc = ((col & 3) << 9) + hid0 + (col >> 2);   // gate*512 + hid
        short8 vh, vm;
        #pragma unroll
        for (int j = 0; j < 8; ++j) {
            float w = Wh[(size_t)(k0 + j) * G4 + gc];
            ushort c0 = bf16r(w);
            vh[j] = (short)c0; vm[j] = (short)bf16r(w - bf16f(c0));
        }
        int base = col * 512 + (k0 ^ ((col & 7) << 3));
        *(short8*)&sWhi[base]  = vh;
        *(short8*)&sWmid[base] = vm;
    }
    if (tid < 64) {
        int gc = ((tid & 3) << 9) + hid0 + (tid >> 2);
        sBias[tid] = bias[gc];
        #pragma unroll
        for (int f = 0; f < 3; ++f) sWi[f * 64 + tid] = Wi[(size_t)f * G4 + gc];
    }

    // ---- placement detection: is group g XCD-uniform? ----
    unsigned xcc;
    asm volatile("s_getreg_b32 %0, hwreg(HW_REG_XCC_ID)" : "=s"(xcc));
    if (tid == 0 && slice == 0)
        __hip_atomic_store(&bar[XCCOF(g)], xcc, __ATOMIC_RELAXED, __HIP_MEMORY_SCOPE_AGENT);
    dev_barrier(bar);
    if (tid == 0) {
        unsigned lx = __hip_atomic_load(&bar[XCCOF(g)], __ATOMIC_RELAXED,
                                        __HIP_MEMORY_SCOPE_AGENT);
        if (lx != xcc)
            __hip_atomic_fetch_or(&bar[BADF(g)], 1u, __ATOMIC_RELAXED,
                                  __HIP_MEMORY_SCOPE_AGENT);
    }
    dev_barrier(bar);
    if (tid == 0)
        sFlag[0] = (__hip_atomic_load(&bar[BADF(g)], __ATOMIC_RELAXED,
                                      __HIP_MEMORY_SCOPE_AGENT) == 0u) ? 1u : 0u;
    __syncthreads();

    if (sFlag[0])
        run_steps<true >(x, lns, lnb, Wd, bd, out, hbHi, hbMid, bar,
                         sWhi, sWmid, zL, sWi, sBias, sX, g, slice);
    else
        run_steps<false>(x, lns, lnb, Wd, bd, out, hbHi, hbMid, bar,
                         sWhi, sWmid, zL, sWi, sBias, sX, g, slice);
}

extern "C" void kernel_launch(void* const* d_in, const int* in_sizes, int n_in,
                              void* d_out, int out_size, void* d_ws, size_t ws_size,
                              hipStream_t stream) {
    const float* x   = (const float*)d_in[0];
    const float* Wi  = (const float*)d_in[1];
    const float* Wh  = (const float*)d_in[2];
    const float* b   = (const float*)d_in[3];
    const float* lns = (const float*)d_in[4];
    const float* lnb = (const float*)d_in[5];
    const float* Wd  = (const float*)d_in[6];
    const float* bd  = (const float*)d_in[7];
    float* out = (float*)d_out;

    // ws: hbHi 3x256x512 ushort (768 KB) | hbMid (768 KB) | bar (~36 KB)
    ushort* hbHi  = (ushort*)d_ws;
    ushort* hbMid = hbHi + (size_t)3 * HTOT;
    unsigned* bar = (unsigned*)(hbMid + (size_t)3 * HTOT);

    hipMemsetAsync(bar, 0, 40960, stream);

    size_t smem = 150544;
    hipFuncSetAttribute((const void*)lstm_v13,
                        hipFuncAttributeMaxDynamicSharedMemorySize, (int)smem);

    void* args[] = { (void*)&x, (void*)&Wi, (void*)&Wh, (void*)&b, (void*)&lns,
                     (void*)&lnb, (void*)&Wd, (void*)&bd, (void*)&out,
                     (void*)&hbHi, (void*)&hbMid, (void*)&bar };
    hipLaunchCooperativeKernel((void*)lstm_v13, dim3(NWG), dim3(NTHR),
                               args, (unsigned int)smem, stream);
}

// Round 14
// 2266.201 us; speedup vs baseline: 1.3532x; 1.2630x over previous
//
#include <hip/hip_runtime.h>

#define BB 256
#define TT 512
#define HH 512
#define G4 2048
#define NTHR 512
#define NWG 256
#define GROUPS 8
#define SLICES 32
#define HTOT (BB*HH)

// bar word layout: per-(g,slice) flag on its own 128-B line, then control words
#define FLAGW(g,s) ((((g)*SLICES)+(s))*32)
#define DCNT     8192
#define DGEN     8208
#define XCCOF(g) (8224+(g))
#define BADF(g)  (8240+(g))

typedef __attribute__((ext_vector_type(8))) short short8;
typedef __attribute__((ext_vector_type(4))) float f32x4;

__device__ __forceinline__ ushort bf16r(float f) {          // RNE fp32->bf16
    unsigned u = __float_as_uint(f);
    return (ushort)((u + 0x7FFFu + ((u >> 16) & 1u)) >> 16);
}
__device__ __forceinline__ float bf16f(ushort s) {
    return __uint_as_float(((unsigned)s) << 16);
}
__device__ __forceinline__ float fsig(float x) {
    float e = exp2f(fminf(-1.44269504f * x, 80.f));
    return 1.f / (1.f + e);
}
__device__ __forceinline__ float ftanh(float x) {
    float e = exp2f(fminf(-2.88539008f * x, 80.f));
    return (1.f - e) / (1.f + e);
}

#define WAITV(n) do { asm volatile("s_waitcnt vmcnt(" #n ")" ::: "memory"); \
                      __builtin_amdgcn_sched_barrier(0); } while (0)

// one-shot data accesses (h planes). Flag polling is ALWAYS atomic (r9/r10 law).
template<bool SC1>
__device__ __forceinline__ void lda16(short8* d, const ushort* p) {
    if constexpr (SC1)
        asm volatile("global_load_dwordx4 %0, %1, off sc0 sc1" : "=v"(*d) : "v"(p));
    else
        asm volatile("global_load_dwordx4 %0, %1, off sc0" : "=v"(*d) : "v"(p));
}
template<bool SC1>
__device__ __forceinline__ void sts2(ushort* p, unsigned v) {
    if constexpr (SC1)
        asm volatile("global_store_short %0, %1, off sc0 sc1" :: "v"(p), "v"(v) : "memory");
    else
        asm volatile("global_store_short %0, %1, off" :: "v"(p), "v"(v) : "memory");
}

__device__ void dev_barrier(unsigned* bar) {
    __syncthreads();
    if (threadIdx.x == 0) {
        unsigned old = __hip_atomic_load(bar + DGEN, __ATOMIC_RELAXED, __HIP_MEMORY_SCOPE_AGENT);
        unsigned a = __hip_atomic_fetch_add(bar + DCNT, 1u, __ATOMIC_RELAXED, __HIP_MEMORY_SCOPE_AGENT);
        if (a == NWG - 1) {
            __hip_atomic_store(bar + DCNT, 0u, __ATOMIC_RELAXED, __HIP_MEMORY_SCOPE_AGENT);
            __hip_atomic_fetch_add(bar + DGEN, 1u, __ATOMIC_RELAXED, __HIP_MEMORY_SCOPE_AGENT);
        } else {
            int sp = 0;
            while (__hip_atomic_load(bar + DGEN, __ATOMIC_RELAXED, __HIP_MEMORY_SCOPE_AGENT) == old
                   && ++sp < (1 << 20))
                __builtin_amdgcn_s_sleep(2);
        }
    }
    __syncthreads();
}

template<bool FAST>
__device__ void run_steps(const float* __restrict__ x, const float* __restrict__ lns,
                          const float* __restrict__ lnb, const float* __restrict__ Wd,
                          const float* __restrict__ bd, float* __restrict__ out,
                          ushort* __restrict__ hbHi, ushort* __restrict__ hbMid,
                          unsigned* __restrict__ bar, short* sWhi, short* sWmid,
                          float* zL, float* sWi, float* sBias, float* sX,
                          int g, int slice)
{
    const int tid = threadIdx.x;
    const int wave = tid >> 6, lane = tid & 63;
    const int rt = wave >> 2, ksq = wave & 3;      // 2 row-tiles x 4 K-quarters
    const int cl = lane & 15, kq4 = (lane >> 4) << 2, kq8 = (lane >> 4) << 3;
    const int grow0 = g * 32, hid0 = slice * 16;
    const int rbase = rt * 16 + kq4;
    const int arow = grow0 + rt * 16 + cl;
    const int bswz = (cl & 7) << 3;
    // gate-phase mapping: one (row, hidden-unit) per thread
    const int grow = tid >> 4, ghq = tid & 15, glc = ghq << 2;

    // ---- hoist B fragments into registers (step-invariant) ----
    short8 Bh[4][4], Bm[4][4];
    #pragma unroll
    for (int c = 0; c < 4; ++c) {
        #pragma unroll
        for (int kc = 0; kc < 4; ++kc) {
            int bo = (c*16 + cl)*512 + ((ksq*128 + kc*32 + kq8) ^ bswz);
            Bh[c][kc] = *(const short8*)&sWhi[bo];
            Bm[c][kc] = *(const short8*)&sWmid[bo];
        }
    }
    // stage x for it = 0
    if (tid < 32) {
        const float* xp = x + ((size_t)(grow0 + tid) * TT + 0) * 3;
        sX[tid*3+0] = xp[0]; sX[tid*3+1] = xp[1]; sX[tid*3+2] = xp[2];
    }
    __syncthreads();      // all waves done reading W LDS; zL may now alias it

    float creg = 0.f;

    for (int it = 0; it <= TT; ++it) {
        const ushort* hiIn = hbHi + (size_t)(it % 3) * HTOT;
        const ushort* mdIn = hbMid + (size_t)(it % 3) * HTOT;
        ushort* hiOut = hbHi + (size_t)((it + 1) % 3) * HTOT;
        ushort* mdOut = hbMid + (size_t)((it + 1) % 3) * HTOT;
        const float* sXc = sX + (it & 1) * 96;
        float*       sXn = sX + ((it + 1) & 1) * 96;

        if (it < TT) {
            f32x4 acc[4];
            #pragma unroll
            for (int c = 0; c < 4; ++c) acc[c] = (f32x4){0.f,0.f,0.f,0.f};
            if (ksq == 0) {               // xg + bias folded into the ksq=0 partial
                #pragma unroll
                for (int c = 0; c < 4; ++c) {
                    int col = c*16 + cl;
                    float b0 = sBias[col], w0 = sWi[col];
                    float w1 = sWi[64+col], w2 = sWi[128+col];
                    #pragma unroll
                    for (int q = 0; q < 4; ++q) {
                        const float* xr = &sXc[(rbase + q) * 3];
                        acc[c][q] = b0 + xr[0]*w0 + xr[1]*w1 + xr[2]*w2;
                    }
                }
            }
            if (it > 0) {
                // per-wave producer gate: this K-quarter's 8 producer flags >= it
                {
                    const unsigned tgt = (unsigned)it;
                    int spins = 0;
                    while (true) {
                        unsigned v = tgt;
                        if (lane < 8)
                            v = __hip_atomic_load(&bar[FLAGW(g, ksq*8 + lane)],
                                                  __ATOMIC_RELAXED, __HIP_MEMORY_SCOPE_AGENT);
                        if (__all(v >= tgt)) break;
                        if (++spins > (1 << 16)) break;
                    }
                }
                const ushort* aHi = hiIn + (size_t)arow * HH + ksq*128 + kq8;
                const ushort* aMd = mdIn + (size_t)arow * HH + ksq*128 + kq8;
                short8 A[8];
                #pragma unroll
                for (int kc = 0; kc < 4; ++kc) {
                    lda16<!FAST>(&A[kc*2],   aHi + kc*32);
                    lda16<!FAST>(&A[kc*2+1], aMd + kc*32);
                }
                #pragma unroll
                for (int kc = 0; kc < 4; ++kc) {
                    if      (kc == 0) WAITV(6);
                    else if (kc == 1) WAITV(4);
                    else if (kc == 2) WAITV(2);
                    else              WAITV(0);
                    short8 Ah = A[kc*2], Am = A[kc*2+1];
                    #pragma unroll
                    for (int c = 0; c < 4; ++c) {
                        acc[c] = __builtin_amdgcn_mfma_f32_16x16x32_bf16(Ah, Bh[c][kc], acc[c], 0,0,0);
                        acc[c] = __builtin_amdgcn_mfma_f32_16x16x32_bf16(Ah, Bm[c][kc], acc[c], 0,0,0);
                        acc[c] = __builtin_amdgcn_mfma_f32_16x16x32_bf16(Am, Bh[c][kc], acc[c], 0,0,0);
                    }
                }
            }
            // ---- publish K-quarter partials to LDS: zL[ksq][row][col] ----
            #pragma unroll
            for (int c = 0; c < 4; ++c) {
                #pragma unroll
                for (int q = 0; q < 4; ++q)
                    zL[(ksq*32 + rbase + q)*68 + c*16 + cl] = acc[c][q];
            }
            __syncthreads();

            // ---- gate phase: 1 (row, hidden) unit per thread ----
            {
                f32x4 z0 = *(const f32x4*)&zL[(grow      )*68 + glc];
                f32x4 z1 = *(const f32x4*)&zL[( 32 + grow)*68 + glc];
                f32x4 z2 = *(const f32x4*)&zL[( 64 + grow)*68 + glc];
                f32x4 z3 = *(const f32x4*)&zL[( 96 + grow)*68 + glc];
                float z[4];
                #pragma unroll
                for (int g3 = 0; g3 < 4; ++g3)
                    z[g3] = (z0[g3] + z1[g3]) + (z2[g3] + z3[g3]);
                float ig = fsig(z[0]), fg = fsig(z[1]);
                float gv = ftanh(z[2]), og = fsig(z[3]);
                creg = fg * creg + ig * gv;
                float hv = og * ftanh(creg);
                ushort h0 = bf16r(hv);
                ushort h1 = bf16r(hv - bf16f(h0));
                size_t ridx = (size_t)(grow0 + grow) * HH + hid0 + ghq;
                sts2<!FAST>(hiOut + ridx, (unsigned)h0);
                sts2<!FAST>(mdOut + ridx, (unsigned)h1);
            }
            // ---- prefetch next step's x into the other sX slot ----
            if (tid < 32 && it + 1 < TT) {
                const float* xp = x + ((size_t)(grow0 + tid) * TT + (it + 1)) * 3;
                sXn[tid*3+0] = xp[0]; sXn[tid*3+1] = xp[1]; sXn[tid*3+2] = xp[2];
            }
            __syncthreads();                  // drains h stores (+x loads) into L2
            if (tid == 0)                     // publish: this wg's h_it is visible
                __hip_atomic_store(&bar[FLAGW(g, slice)], (unsigned)(it + 1),
                                   __ATOMIC_RELAXED, __HIP_MEMORY_SCOPE_AGENT);
        }

        // ---- output head for t=it-1 on wave 1 (covered by step-it gating) ----
        if (it >= 1 && wave == 1) {
            if (it == TT) {   // final: no MFMA gating ran -> explicit 32-flag check
                const unsigned tgt = (unsigned)TT;
                int spins = 0;
                while (true) {
                    unsigned v = tgt;
                    if (lane < 32)
                        v = __hip_atomic_load(&bar[FLAGW(g, lane)],
                                              __ATOMIC_RELAXED, __HIP_MEMORY_SCOPE_AGENT);
                    if (__all(v >= tgt)) break;
                    if (++spins > (1 << 16)) break;
                }
            }
            const int row_h = grow0 + slice;
            const ushort* hp = hiIn + (size_t)row_h * HH + lane * 8;
            short8 vh, vm;
            lda16<!FAST>(&vh, hp);
            lda16<!FAST>(&vm, mdIn + (size_t)row_h * HH + lane * 8);
            WAITV(0);
            float h[8]; float s = 0.f, ss = 0.f;
            #pragma unroll
            for (int j = 0; j < 8; ++j) {
                h[j] = bf16f((ushort)vh[j]) + bf16f((ushort)vm[j]);
                s += h[j]; ss += h[j] * h[j];
            }
            #pragma unroll
            for (int d = 1; d < 64; d <<= 1) { s += __shfl_xor(s, d); ss += __shfl_xor(ss, d); }
            float mu = s * (1.f / 512.f);
            float rstd = rsqrtf(ss * (1.f / 512.f) - mu * mu + 1e-6f);
            float d0 = 0.f, d1 = 0.f, d2 = 0.f;
            #pragma unroll
            for (int j = 0; j < 8; ++j) {
                int col = lane * 8 + j;
                float y = (h[j] - mu) * rstd * lns[col] + lnb[col];
                y = fmaxf(y, 0.f);
                d0 = fmaf(y, Wd[col*3+0], d0);
                d1 = fmaf(y, Wd[col*3+1], d1);
                d2 = fmaf(y, Wd[col*3+2], d2);
            }
            #pragma unroll
            for (int d = 1; d < 64; d <<= 1) {
                d0 += __shfl_xor(d0, d); d1 += __shfl_xor(d1, d); d2 += __shfl_xor(d2, d);
            }
            if (lane == 0) {
                size_t o = ((size_t)row_h * TT + (it - 1)) * 3;
                out[o + 0] = d0 + bd[0];
                out[o + 1] = d1 + bd[1];
                out[o + 2] = d2 + bd[2];
            }
        }
        // NO end-of-step barrier: next step's per-wave flag gates enforce order.
    }
}

__global__ __launch_bounds__(NTHR, 1)
void lstm_v14(const float* __restrict__ x, const float* __restrict__ Wi,
              const float* __restrict__ Wh, const float* __restrict__ bias,
              const float* __restrict__ lns, const float* __restrict__ lnb,
              const float* __restrict__ Wd, const float* __restrict__ bd,
              float* __restrict__ out, ushort* __restrict__ hbHi,
              ushort* __restrict__ hbMid, unsigned* __restrict__ bar)
{
    extern __shared__ char smem[];
    short* sWhi  = (short*)smem;                    // [64][512] staging  64 KB
    short* sWmid = (short*)(smem + 65536);          // [64][512] staging  64 KB
    float* zL    = (float*)smem;                    // ALIAS: [4][32][68] 34.8 KB
    float* sWi   = (float*)(smem + 131072);         // [3][64]
    float* sBias = (float*)(smem + 131840);         // [64]
    float* sX    = (float*)(smem + 132096);         // [2][96] x double-buffer
    unsigned* sFlag = (unsigned*)(smem + 132864);

    const int bid = blockIdx.x, tid = threadIdx.x;
    const int g = bid & 7, slice = bid >> 3;        // group = XCD under round-robin
    const int hid0 = slice * 16;

    // ---- prologue: decompose W slice (64 gc x 512 k) into 2 LDS planes ----
    for (int cc = tid; cc < 4096; cc += NTHR) {
        int col = cc & 63, k0 = (cc >> 6) << 3;
        int gc = ((col & 3) << 9) + hid0 + (col >> 2);   // gate*512 + hid
        short8 vh, vm;
        #pragma unroll
        for (int j = 0; j < 8; ++j) {
            float w = Wh[(size_t)(k0 + j) * G4 + gc];
            ushort c0 = bf16r(w);
            vh[j] = (short)c0; vm[j] = (short)bf16r(w - bf16f(c0));
        }
        int base = col * 512 + (k0 ^ ((col & 7) << 3));
        *(short8*)&sWhi[base]  = vh;
        *(short8*)&sWmid[base] = vm;
    }
    if (tid < 64) {
        int gc = ((tid & 3) << 9) + hid0 + (tid >> 2);
        sBias[tid] = bias[gc];
        #pragma unroll
        for (int f = 0; f < 3; ++f) sWi[f * 64 + tid] = Wi[(size_t)f * G4 + gc];
    }

    // ---- placement detection: is group g XCD-uniform? ----
    unsigned xcc;
    asm volatile("s_getreg_b32 %0, hwreg(HW_REG_XCC_ID)" : "=s"(xcc));
    if (tid == 0 && slice == 0)
        __hip_atomic_store(&bar[XCCOF(g)], xcc, __ATOMIC_RELAXED, __HIP_MEMORY_SCOPE_AGENT);
    dev_barrier(bar);
    if (tid == 0) {
        unsigned lx = __hip_atomic_load(&bar[XCCOF(g)], __ATOMIC_RELAXED,
                                        __HIP_MEMORY_SCOPE_AGENT);
        if (lx != xcc)
            __hip_atomic_fetch_or(&bar[BADF(g)], 1u, __ATOMIC_RELAXED,
                                  __HIP_MEMORY_SCOPE_AGENT);
    }
    dev_barrier(bar);
    if (tid == 0)
        sFlag[0] = (__hip_atomic_load(&bar[BADF(g)], __ATOMIC_RELAXED,
                                      __HIP_MEMORY_SCOPE_AGENT) == 0u) ? 1u : 0u;
    __syncthreads();

    if (sFlag[0])
        run_steps<true >(x, lns, lnb, Wd, bd, out, hbHi, hbMid, bar,
                         sWhi, sWmid, zL, sWi, sBias, sX, g, slice);
    else
        run_steps<false>(x, lns, lnb, Wd, bd, out, hbHi, hbMid, bar,
                         sWhi, sWmid, zL, sWi, sBias, sX, g, slice);
}

extern "C" void kernel_launch(void* const* d_in, const int* in_sizes, int n_in,
                              void* d_out, int out_size, void* d_ws, size_t ws_size,
                              hipStream_t stream) {
    const float* x   = (const float*)d_in[0];
    const float* Wi  = (const float*)d_in[1];
    const float* Wh  = (const float*)d_in[2];
    const float* b   = (const float*)d_in[3];
    const float* lns = (const float*)d_in[4];
    const float* lnb = (const float*)d_in[5];
    const float* Wd  = (const float*)d_in[6];
    const float* bd  = (const float*)d_in[7];
    float* out = (float*)d_out;

    // ws: hbHi 3x256x512 ushort (768 KB) | hbMid (768 KB) | bar (~36 KB)
    ushort* hbHi  = (ushort*)d_ws;
    ushort* hbMid = hbHi + (size_t)3 * HTOT;
    unsigned* bar = (unsigned*)(hbMid + (size_t)3 * HTOT);

    hipMemsetAsync(bar, 0, 40960, stream);

    size_t smem = 132880;
    hipFuncSetAttribute((const void*)lstm_v14,
                        hipFuncAttributeMaxDynamicSharedMemorySize, (int)smem);

    void* args[] = { (void*)&x, (void*)&Wi, (void*)&Wh, (void*)&b, (void*)&lns,
                     (void*)&lnb, (void*)&Wd, (void*)&bd, (void*)&out,
                     (void*)&hbHi, (void*)&hbMid, (void*)&bar };
    hipLaunchCooperativeKernel((void*)lstm_v14, dim3(NWG), dim3(NTHR),
                               args, (unsigned int)smem, stream);
}